// Round 11
// baseline (1372.610 us; speedup 1.0000x reference)
//
#include <hip/hip_runtime.h>

typedef unsigned short ushort;
typedef unsigned int uint;
typedef __bf16 bf16_t;
typedef bf16_t bf16x8 __attribute__((ext_vector_type(8)));
typedef float f32x4 __attribute__((ext_vector_type(4)));

#define B_ 2048
#define T_ 512
#define D_ 5
#define H_ 128
#define C_ 10
#define BT 16      // rows per pair (MFMA m-tile)
#define BLK 512    // 8 waves, 2 waves/SIMD
#define NBLK 64    // producer blocks (each owns 2 pairs = 32 rows)
#define F_ 32      // ring slots (caps L2 footprint; >= 2*CH+CH)
#define CH 8       // steps per sync chunk
#define H0STR 168  // producer LDS row stride (h0 128 + x 32 + pad)
#define H1STR 136  // consumer LDS row stride (128 + 8 pad)

static __device__ __forceinline__ float b2f(ushort u) {
    return __builtin_bit_cast(float, ((uint)u) << 16);
}
static __device__ __forceinline__ ushort f2b(float f) {
    uint u = __builtin_bit_cast(uint, f);
    u += 0x7FFFu + ((u >> 16) & 1u);   // RNE
    return (ushort)(u >> 16);
}
// inf-safe: exp->inf => rcp->0 => sigmoid->0/1, tanh->+-1
static __device__ __forceinline__ float sigf(float x) {
    return __builtin_amdgcn_rcpf(1.0f + __expf(-x));
}
static __device__ __forceinline__ float tanhf_(float x) {
    return 1.0f - 2.0f * __builtin_amdgcn_rcpf(1.0f + __expf(2.0f * x));
}
static __device__ __forceinline__ float ldf(const void* p, long i, bool m32) {
    return m32 ? ((const float*)p)[i] : b2f(((const ushort*)p)[i]);
}
static __device__ __forceinline__ bf16x8 ld16(const ushort* p) {
    return __builtin_bit_cast(bf16x8, *(const uint4*)p);
}
static __device__ __forceinline__ bf16x8 ldfrag(const void* p, long idx, bool m32) {
    if (!m32) return ld16((const ushort*)p + idx);
    const float* f = (const float*)p + idx;
    union { ushort u[8]; bf16x8 v; } r;
#pragma unroll
    for (int j = 0; j < 8; ++j) r.u[j] = f2b(f[j]);
    return r.v;
}
static __device__ __forceinline__ f32x4 splat4(float v) {
    f32x4 r = {v, v, v, v};
    return r;
}
// LDS-only barrier: skips the compiler's vmcnt(0) drain (FIFO stores/prefetches
// stay in flight across steps; their visibility is chunk-gated).
static __device__ __forceinline__ void bar_fast() {
    asm volatile("s_waitcnt lgkmcnt(0)\n\ts_barrier" ::: "memory");
}

// ---- dtype detector (proven R2-R10; picks f32)
__global__ void detect_dtype(const ushort* __restrict__ w, int* __restrict__ flag) {
    __shared__ int cnt;
    if (threadIdx.x == 0) cnt = 0;
    __syncthreads();
    int local = 0;
    for (int i = threadIdx.x; i < 16384; i += 256)
        if ((uint)(w[i] & 0x7F80u) >= 0x4180u) ++local;   // |v| >= 16
    atomicAdd(&cnt, local);
    __syncthreads();
    if (threadIdx.x == 0) *flag = (cnt > 512) ? 1 : 0;
}

// ---- zero pipeline progress flags each launch (d_ws is poisoned)
__global__ void init_flags(int* __restrict__ prog) {
    prog[threadIdx.x] = 0;   // 256 ints: prog_p[64] @0 | prog_c[64] @128
}

// =====================================================================
// R11: R6 skeleton x TWO independent pairs per block.
// blocks 0..63 = layer-0 producers (32 rows each); 64..127 = layer-1
// consumers + classifier. Per-step raw lgkm barrier; full-drain
// __syncthreads only at chunk boundaries (before flag release).
// =====================================================================
__global__ __launch_bounds__(BLK, 2) void lstm2_pipe2(
    const void* __restrict__ x,
    const void* __restrict__ wih0, const void* __restrict__ whh0,
    const void* __restrict__ bih0, const void* __restrict__ bhh0,
    const void* __restrict__ wih1, const void* __restrict__ whh1,
    const void* __restrict__ bih1, const void* __restrict__ bhh1,
    const void* __restrict__ cw1, const void* __restrict__ cb1,
    const void* __restrict__ cw2, const void* __restrict__ cb2,
    const int* __restrict__ flag,
    ushort* __restrict__ fifo, int* __restrict__ prog_p, int* __restrict__ prog_c,
    void* __restrict__ out)
{
    __shared__ __align__(16) ushort sAp[2][2][BT * H0STR]; // producer: [pair][buf]
    __shared__ __align__(16) ushort sAc[2][2][BT * H1STR]; // consumer staged h0
    __shared__ __align__(16) ushort sBc[2][2][BT * H1STR]; // consumer h1
    __shared__ float rs[32 * 64];                          // classifier hidden

    const bool m32 = (*flag) != 0;
    const int tid  = threadIdx.x;
    const int w    = tid >> 6;
    const int lane = tid & 63;
    const int quad = lane >> 4;
    const int l16  = lane & 15;

    if ((int)blockIdx.x < NBLK) {
        // ================= PRODUCER: layer 0, pairs A/B =================
        const int b   = blockIdx.x;
        const int bt0 = b * 32;
        ushort* ff[2] = { fifo + (long)(b * 2)     * F_ * (BT * H_),
                          fifo + (long)(b * 2 + 1) * F_ * (BT * H_) };

        // stage x(0) into x-region of buf0; zeros into buf1
        for (int i = tid; i < 2 * BT * 32; i += BLK) {
            int q = i >> 9, j = i & 511, row = j >> 5, cc = j & 31;
            ushort v0 = 0;
            if (cc < 5)
                v0 = f2b(ldf(x, ((long)(bt0 + q * 16 + row) * T_) * D_ + cc, m32));
            sAp[q][0][row * H0STR + 128 + cc] = v0;
            sAp[q][1][row * H0STR + 128 + cc] = 0;
        }

        // shared weights: w_hh0 frags + x-tile frags (~190 regs/wave total)
        bf16x8 wh0c[4][4];
        bf16x8 xbf[4];
        float  b0v[4];
#pragma unroll
        for (int g = 0; g < 4; ++g) {
            const int n = g * 128 + w * 16 + l16;
#pragma unroll
            for (int kt = 0; kt < 4; ++kt)
                wh0c[g][kt] = ldfrag(whh0, (long)n * 128 + kt * 32 + quad * 8, m32);
            union { ushort u[8]; bf16x8 v; } xt;
#pragma unroll
            for (int j = 0; j < 8; ++j) xt.u[j] = 0;
            if (quad == 0) {
#pragma unroll
                for (int j = 0; j < 5; ++j) xt.u[j] = f2b(ldf(wih0, (long)n * D_ + j, m32));
            }
            xbf[g] = xt.v;
            b0v[g] = ldf(bih0, n, m32) + ldf(bhh0, n, m32);
        }
        __syncthreads();

        bf16x8 h0f[2][4];
        {
            uint4 z = make_uint4(0, 0, 0, 0);
#pragma unroll
            for (int q = 0; q < 2; ++q)
#pragma unroll
                for (int kt = 0; kt < 4; ++kt)
                    h0f[q][kt] = __builtin_bit_cast(bf16x8, z); // h0(-1)=0
        }
        f32x4 c0[2] = {splat4(0.f), splat4(0.f)};
        const int pr = (tid < 80) ? 0 : ((tid < 160) ? 1 : -1); // x loader pair
        int xr = 0, xc = 0; long xoff = 0;
        if (pr >= 0) {
            int s = tid - pr * 80;
            xr = s / 5; xc = s - xr * 5;
            xoff = ((long)(bt0 + pr * 16 + xr) * T_ + 1) * D_ + xc;
        }

#pragma unroll 1
        for (int t = 0; t < T_; ++t) {
            const int rb = t & 1, wb = (t + 1) & 1;
            if ((t & (CH - 1)) == 0 && t > 0) {
                __syncthreads();    // full drain: all waves' FIFO stores complete
                if (tid == 0) {
                    __hip_atomic_store(&prog_p[b], t, __ATOMIC_RELEASE,
                                       __HIP_MEMORY_SCOPE_AGENT);
                    int need = t + CH - F_;   // ring WAR throttle
                    if (need > 0)
                        while (__hip_atomic_load(&prog_c[b], __ATOMIC_ACQUIRE,
                                                 __HIP_MEMORY_SCOPE_AGENT) < need)
                            __builtin_amdgcn_s_sleep(2);
                }
                __syncthreads();
            }
            // off-path: load x(t+1)
            float xv = 0.f;
            const bool stg = (pr >= 0) && (t < T_ - 1);
            if (stg) { xv = ldf(x, xoff, m32); xoff += D_; }

            // ---- two independent hot chains: a[q] = b0 + whh0·h0_q(t-1) + x_q(t)·W
            f32x4 a[2][4];
#pragma unroll
            for (int q = 0; q < 2; ++q)
#pragma unroll
                for (int g = 0; g < 4; ++g) a[q][g] = splat4(b0v[g]);
#pragma unroll
            for (int kt = 0; kt < 4; ++kt)
#pragma unroll
                for (int q = 0; q < 2; ++q)
#pragma unroll
                    for (int g = 0; g < 4; ++g)
                        a[q][g] = __builtin_amdgcn_mfma_f32_16x16x32_bf16(
                            h0f[q][kt], wh0c[g][kt], a[q][g], 0, 0, 0);
#pragma unroll
            for (int q = 0; q < 2; ++q) {
                bf16x8 ha4 = ld16(&sAp[q][rb][l16 * H0STR + 128 + quad * 8]);
#pragma unroll
                for (int g = 0; g < 4; ++g)
                    a[q][g] = __builtin_amdgcn_mfma_f32_16x16x32_bf16(
                        ha4, xbf[g], a[q][g], 0, 0, 0);
            }
#pragma unroll
            for (int q = 0; q < 2; ++q) {
                ushort* fs = ff[q] + (long)(t & (F_ - 1)) * (BT * H_);
#pragma unroll
                for (int r = 0; r < 4; ++r) {
                    float iv = sigf(a[q][0][r]), fv = sigf(a[q][1][r]);
                    float gv = tanhf_(a[q][2][r]), ov = sigf(a[q][3][r]);
                    float cv = fv * c0[q][r] + iv * gv;
                    c0[q][r] = cv;
                    ushort hv = f2b(ov * tanhf_(cv));
                    sAp[q][wb][(quad * 4 + r) * H0STR + w * 16 + l16] = hv;
                    fs[(quad * 4 + r) * H_ + w * 16 + l16] = hv;   // FIFO
                }
            }
            if (stg) sAp[pr][wb][xr * H0STR + 128 + xc] = f2b(xv); // x(t+1)

            bar_fast();   // LDS-only barrier (no vmcnt drain)
#pragma unroll
            for (int q = 0; q < 2; ++q)
#pragma unroll
                for (int kt = 0; kt < 4; ++kt)
                    h0f[q][kt] = ld16(&sAp[q][wb][l16 * H0STR + kt * 32 + quad * 8]);
        }
        __syncthreads();   // drain final chunk's FIFO stores
        if (tid == 0)
            __hip_atomic_store(&prog_p[b], T_, __ATOMIC_RELEASE,
                               __HIP_MEMORY_SCOPE_AGENT);
    } else {
        // ================= CONSUMER: layer 1 + classifier, pairs A/B ==========
        const int b   = blockIdx.x - NBLK;
        const int bt0 = b * 32;
        const ushort* ff[2] = { fifo + (long)(b * 2)     * F_ * (BT * H_),
                                fifo + (long)(b * 2 + 1) * F_ * (BT * H_) };

        // zero h1(-1)
        for (int i = tid; i < 2 * BT * H_; i += BLK) {
            int q = i >> 11, j = i & 2047, row = j >> 7, cc = j & 127;
            sBc[q][0][row * H1STR + cc] = 0;
        }

        // shared weights: w_ih1 + w_hh1 frags (~185 regs/wave total)
        bf16x8 wi1f[4][4], wh1f[4][4];
        float  b1v[4];
#pragma unroll
        for (int g = 0; g < 4; ++g) {
            const int n = g * 128 + w * 16 + l16;
#pragma unroll
            for (int kt = 0; kt < 4; ++kt) {
                wi1f[g][kt] = ldfrag(wih1, (long)n * 128 + kt * 32 + quad * 8, m32);
                wh1f[g][kt] = ldfrag(whh1, (long)n * 128 + kt * 32 + quad * 8, m32);
            }
            b1v[g] = ldf(bih1, n, m32) + ldf(bhh1, n, m32);
        }

        // wait for first two chunks, then stage slot 0 of both pairs
        if (tid == 0) {
            while (__hip_atomic_load(&prog_p[b], __ATOMIC_ACQUIRE,
                                     __HIP_MEMORY_SCOPE_AGENT) < 2 * CH)
                __builtin_amdgcn_s_sleep(2);
        }
        __syncthreads();
        {
            int row = tid >> 5, col4 = (tid & 31) * 4;
#pragma unroll
            for (int q = 0; q < 2; ++q) {
                uint2 d = *(const uint2*)(ff[q] + tid * 4);
                *(uint2*)&sAc[q][0][row * H1STR + col4] = d;
            }
        }
        __syncthreads();

        f32x4 c1[2] = {splat4(0.f), splat4(0.f)};
        const int srow = tid >> 5, scol4 = (tid & 31) * 4;

#pragma unroll 1
        for (int t = 0; t < T_; ++t) {
            const int rb = t & 1, wb = (t + 1) & 1;
            if (((t + 1) & (CH - 1)) == 0 && t + 1 < T_) {
                __syncthreads();    // full drain before release of consumed slots
                if (tid == 0) {
                    int target = t + 1 + CH;
                    if (target > T_) target = T_;
                    while (__hip_atomic_load(&prog_p[b], __ATOMIC_ACQUIRE,
                                             __HIP_MEMORY_SCOPE_AGENT) < target)
                        __builtin_amdgcn_s_sleep(2);
                    __hip_atomic_store(&prog_c[b], t + 1, __ATOMIC_RELEASE,
                                       __HIP_MEMORY_SCOPE_AGENT);
                }
                __syncthreads();
            }
            // off-path: prefetch h0(t+1) for both pairs
            uint2 pf[2];
            const bool hn = (t + 1 < T_);
            if (hn) {
#pragma unroll
                for (int q = 0; q < 2; ++q)
                    pf[q] = *(const uint2*)(ff[q]
                            + (long)((t + 1) & (F_ - 1)) * (BT * H_) + tid * 4);
            }

            // ---- two independent hot chains: a[q] = b1 + wi1f·h0_q(t) + wh1f·h1_q(t-1)
            f32x4 a[2][4];
#pragma unroll
            for (int q = 0; q < 2; ++q)
#pragma unroll
                for (int g = 0; g < 4; ++g) a[q][g] = splat4(b1v[g]);
#pragma unroll
            for (int kt = 0; kt < 4; ++kt)
#pragma unroll
                for (int q = 0; q < 2; ++q) {
                    bf16x8 h0a = ld16(&sAc[q][rb][l16 * H1STR + kt * 32 + quad * 8]);
#pragma unroll
                    for (int g = 0; g < 4; ++g)
                        a[q][g] = __builtin_amdgcn_mfma_f32_16x16x32_bf16(
                            h0a, wi1f[g][kt], a[q][g], 0, 0, 0);
                }
#pragma unroll
            for (int kt = 0; kt < 4; ++kt)
#pragma unroll
                for (int q = 0; q < 2; ++q) {
                    bf16x8 hb = ld16(&sBc[q][rb][l16 * H1STR + kt * 32 + quad * 8]);
#pragma unroll
                    for (int g = 0; g < 4; ++g)
                        a[q][g] = __builtin_amdgcn_mfma_f32_16x16x32_bf16(
                            hb, wh1f[g][kt], a[q][g], 0, 0, 0);
                }
#pragma unroll
            for (int q = 0; q < 2; ++q)
#pragma unroll
                for (int r = 0; r < 4; ++r) {
                    float iv = sigf(a[q][0][r]), fv = sigf(a[q][1][r]);
                    float gv = tanhf_(a[q][2][r]), ov = sigf(a[q][3][r]);
                    float cv = fv * c1[q][r] + iv * gv;
                    c1[q][r] = cv;
                    sBc[q][wb][(quad * 4 + r) * H1STR + w * 16 + l16]
                        = f2b(ov * tanhf_(cv));
                }
            if (hn) {
#pragma unroll
                for (int q = 0; q < 2; ++q)
                    *(uint2*)&sAc[q][wb][srow * H1STR + scol4] = pf[q];
            }
            bar_fast();   // LDS-only barrier
        }
        __syncthreads();  // ensure last sBc writes visible (belt & braces)

        // h1(T-1) is in sBc[q][0]  (t=511 wrote wb=0)
        {
            int m = tid >> 4, j0 = (tid & 15) * 4;   // 32 rows x 16 threads
            float s0 = ldf(cb1, j0, m32), s1 = ldf(cb1, j0 + 1, m32);
            float s2 = ldf(cb1, j0 + 2, m32), s3 = ldf(cb1, j0 + 3, m32);
            const ushort* hr = &sBc[m >> 4][0][(m & 15) * H1STR];
#pragma unroll 4
            for (int k = 0; k < 128; ++k) {
                float hv = b2f(hr[k]);
                s0 += hv * ldf(cw1, (long)j0 * 128 + k, m32);
                s1 += hv * ldf(cw1, (long)(j0 + 1) * 128 + k, m32);
                s2 += hv * ldf(cw1, (long)(j0 + 2) * 128 + k, m32);
                s3 += hv * ldf(cw1, (long)(j0 + 3) * 128 + k, m32);
            }
            rs[m * 64 + j0]     = fmaxf(s0, 0.f);
            rs[m * 64 + j0 + 1] = fmaxf(s1, 0.f);
            rs[m * 64 + j0 + 2] = fmaxf(s2, 0.f);
            rs[m * 64 + j0 + 3] = fmaxf(s3, 0.f);
        }
        __syncthreads();
        if (tid < 320) {
            int m = tid / 10, cc = tid - m * 10;   // 32 rows x 10 classes
            float s = ldf(cb2, cc, m32);
#pragma unroll
            for (int j = 0; j < 64; ++j)
                s += rs[m * 64 + j] * ldf(cw2, (long)cc * 64 + j, m32);
            long oi = (long)(bt0 + m) * C_ + cc;
            if (m32) ((float*)out)[oi] = s; else ((ushort*)out)[oi] = f2b(s);
        }
        for (int idx = tid; idx < 2 * BT * H_; idx += BLK) {
            int m = idx >> 7, k = idx & 127;
            float v = b2f(sBc[m >> 4][0][(m & 15) * H1STR + k]);
            long oi = (long)B_ * C_ + (long)(bt0 + m) * H_ + k;
            if (m32) ((float*)out)[oi] = v; else ((ushort*)out)[oi] = f2b(v);
        }
    }
}

// =====================================================================
// Fallback: proven R5 monolithic kernel (when ws too small for the FIFO)
// =====================================================================
__global__ __launch_bounds__(BLK, 2) void lstm2_mono(
    const void* __restrict__ x,
    const void* __restrict__ wih0, const void* __restrict__ whh0,
    const void* __restrict__ bih0, const void* __restrict__ bhh0,
    const void* __restrict__ wih1, const void* __restrict__ whh1,
    const void* __restrict__ bih1, const void* __restrict__ bhh1,
    const void* __restrict__ cw1, const void* __restrict__ cb1,
    const void* __restrict__ cw2, const void* __restrict__ cb2,
    const int* __restrict__ flag, void* __restrict__ out)
{
    __shared__ __align__(16) ushort h0s[2][BT * H0STR];
    __shared__ __align__(16) ushort h1s[2][BT * H1STR];
    __shared__ float rs[BT * 64];
    __shared__ uint4 xstash[4 * 8 * 64];

    const bool m32 = (*flag) != 0;
    const int tid  = threadIdx.x;
    const int w    = tid >> 6;
    const int lane = tid & 63;
    const int quad = lane >> 4;
    const int l16  = lane & 15;
    const int bt0  = blockIdx.x * BT;

    for (int i = tid; i < BT * 32; i += BLK) {
        int row = i >> 5, cc = i & 31;
        ushort v0 = (cc < 5) ? f2b(ldf(x, ((long)(bt0 + row) * T_) * D_ + cc, m32)) : (ushort)0;
        h0s[0][row * H0STR + 128 + cc] = v0;
        h0s[1][row * H0STR + 128 + cc] = 0;
    }
    for (int i = tid; i < BT * H_; i += BLK) {
        int row = i >> 7, cc = i & 127;
        h1s[1][row * H1STR + cc] = 0;
    }

    bf16x8 wh0c[4][4], wi1f[4][4], wh1f[4][4];
    float  b0v[4], b1v[4];
#pragma unroll
    for (int g = 0; g < 4; ++g) {
        const int n = g * 128 + w * 16 + l16;
#pragma unroll
        for (int kt = 0; kt < 4; ++kt) {
            wh0c[g][kt] = ldfrag(whh0, (long)n * 128 + kt * 32 + quad * 8, m32);
            wi1f[g][kt] = ldfrag(wih1, (long)n * 128 + kt * 32 + quad * 8, m32);
            wh1f[g][kt] = ldfrag(whh1, (long)n * 128 + kt * 32 + quad * 8, m32);
        }
        union { ushort u[8]; uint4 q; } xt;
        xt.q = make_uint4(0, 0, 0, 0);
        if (quad == 0) {
#pragma unroll
            for (int j = 0; j < 5; ++j) xt.u[j] = f2b(ldf(wih0, (long)n * D_ + j, m32));
        }
        xstash[(g * 8 + w) * 64 + lane] = xt.q;
        b0v[g] = ldf(bih0, n, m32) + ldf(bhh0, n, m32);
        b1v[g] = ldf(bih1, n, m32) + ldf(bhh1, n, m32);
    }
    __syncthreads();

    bf16x8 h0f[4];
    {
        uint4 z = make_uint4(0, 0, 0, 0);
        h0f[0] = h0f[1] = h0f[2] = h0f[3] = __builtin_bit_cast(bf16x8, z);
    }
    f32x4 c0 = splat4(0.f), c1 = splat4(0.f);
    const int xr = tid / 5, xc = tid - (tid / 5) * 5;

#pragma unroll 1
    for (int t = 0; t < T_; ++t) {
        const int wb = (t + 1) & 1, rb = t & 1;
        float xv = 0.f;
        const bool stage = (tid < 80) && (t < T_ - 1);
        if (stage) xv = ldf(x, ((long)(bt0 + xr) * T_ + (t + 1)) * D_ + xc, m32);

        f32x4 a[4];
#pragma unroll
        for (int g = 0; g < 4; ++g) a[g] = splat4(b0v[g]);
#pragma unroll
        for (int kt = 0; kt < 4; ++kt)
#pragma unroll
            for (int g = 0; g < 4; ++g)
                a[g] = __builtin_amdgcn_mfma_f32_16x16x32_bf16(
                    h0f[kt], wh0c[g][kt], a[g], 0, 0, 0);
        {
            bf16x8 ha4 = ld16(&h0s[rb][l16 * H0STR + 128 + quad * 8]);
#pragma unroll
            for (int g = 0; g < 4; ++g) {
                bf16x8 xb = __builtin_bit_cast(bf16x8, xstash[(g * 8 + w) * 64 + lane]);
                a[g] = __builtin_amdgcn_mfma_f32_16x16x32_bf16(ha4, xb, a[g], 0, 0, 0);
            }
        }
        ushort h0w[4];
#pragma unroll
        for (int r = 0; r < 4; ++r) {
            float iv = sigf(a[0][r]), fv = sigf(a[1][r]);
            float gv = tanhf_(a[2][r]), ov = sigf(a[3][r]);
            float cv = fv * c0[r] + iv * gv;
            c0[r] = cv;
            h0w[r] = f2b(ov * tanhf_(cv));
        }
#pragma unroll
        for (int r = 0; r < 4; ++r)
            h0s[wb][(quad * 4 + r) * H0STR + w * 16 + l16] = h0w[r];
        if (stage) h0s[wb][xr * H0STR + 128 + xc] = f2b(xv);
        __syncthreads();
#pragma unroll
        for (int kt = 0; kt < 4; ++kt)
            h0f[kt] = ld16(&h0s[wb][l16 * H0STR + kt * 32 + quad * 8]);

#pragma unroll
        for (int g = 0; g < 4; ++g) a[g] = splat4(b1v[g]);
#pragma unroll
        for (int kt = 0; kt < 4; ++kt)
#pragma unroll
            for (int g = 0; g < 4; ++g)
                a[g] = __builtin_amdgcn_mfma_f32_16x16x32_bf16(
                    h0f[kt], wi1f[g][kt], a[g], 0, 0, 0);
#pragma unroll
        for (int kt = 0; kt < 4; ++kt) {
            bf16x8 hb = ld16(&h1s[wb][l16 * H1STR + kt * 32 + quad * 8]);
#pragma unroll
            for (int g = 0; g < 4; ++g)
                a[g] = __builtin_amdgcn_mfma_f32_16x16x32_bf16(
                    hb, wh1f[g][kt], a[g], 0, 0, 0);
        }
#pragma unroll
        for (int r = 0; r < 4; ++r) {
            float iv = sigf(a[0][r]), fv = sigf(a[1][r]);
            float gv = tanhf_(a[2][r]), ov = sigf(a[3][r]);
            float cv = fv * c1[r] + iv * gv;
            c1[r] = cv;
            h1s[wb ^ 1][(quad * 4 + r) * H1STR + w * 16 + l16] = f2b(ov * tanhf_(cv));
        }
    }
    __syncthreads();

    if (tid < 256) {
        int m = tid >> 4, j0 = (tid & 15) * 4;
        float s0 = ldf(cb1, j0, m32), s1 = ldf(cb1, j0 + 1, m32);
        float s2 = ldf(cb1, j0 + 2, m32), s3 = ldf(cb1, j0 + 3, m32);
        const ushort* hr = &h1s[1][m * H1STR];
#pragma unroll 4
        for (int k = 0; k < 128; ++k) {
            float hv = b2f(hr[k]);
            s0 += hv * ldf(cw1, (long)j0 * 128 + k, m32);
            s1 += hv * ldf(cw1, (long)(j0 + 1) * 128 + k, m32);
            s2 += hv * ldf(cw1, (long)(j0 + 2) * 128 + k, m32);
            s3 += hv * ldf(cw1, (long)(j0 + 3) * 128 + k, m32);
        }
        rs[m * 64 + j0]     = fmaxf(s0, 0.f);
        rs[m * 64 + j0 + 1] = fmaxf(s1, 0.f);
        rs[m * 64 + j0 + 2] = fmaxf(s2, 0.f);
        rs[m * 64 + j0 + 3] = fmaxf(s3, 0.f);
    }
    __syncthreads();
    if (tid < 160) {
        int m = tid / 10, cc = tid - m * 10;
        float s = ldf(cb2, cc, m32);
#pragma unroll
        for (int j = 0; j < 64; ++j) s += rs[m * 64 + j] * ldf(cw2, (long)cc * 64 + j, m32);
        long oi = (long)(bt0 + m) * C_ + cc;
        if (m32) ((float*)out)[oi] = s; else ((ushort*)out)[oi] = f2b(s);
    }
    for (int idx = tid; idx < BT * H_; idx += BLK) {
        int m = idx >> 7, k = idx & 127;
        float v = b2f(h1s[1][m * H1STR + k]);
        long oi = (long)B_ * C_ + (long)(bt0 + m) * H_ + k;
        if (m32) ((float*)out)[oi] = v; else ((ushort*)out)[oi] = f2b(v);
    }
}

extern "C" void kernel_launch(void* const* d_in, const int* in_sizes, int n_in,
                              void* d_out, int out_size, void* d_ws, size_t ws_size,
                              hipStream_t stream) {
    (void)in_sizes; (void)n_in; (void)out_size;
    int* prog  = (int*)d_ws;                       // prog_p[64] @0 | prog_c[64] @128
    int* flag  = (int*)((char*)d_ws + 4096);
    ushort* fifo = (ushort*)((char*)d_ws + 8192);

    hipLaunchKernelGGL(detect_dtype, dim3(1), dim3(256), 0, stream,
                       (const ushort*)d_in[2], flag);

    const size_t slot = (size_t)128 * BT * H_ * sizeof(ushort); // 128 pairs, 1 step
    const bool fit = (ws_size >= 8192 + (size_t)F_ * slot);

    if (fit) {
        hipLaunchKernelGGL(init_flags, dim3(1), dim3(256), 0, stream, prog);
        hipLaunchKernelGGL(lstm2_pipe2, dim3(2 * NBLK), dim3(BLK), 0, stream,
                           d_in[0], d_in[1], d_in[2], d_in[3], d_in[4],
                           d_in[5], d_in[6], d_in[7], d_in[8],
                           d_in[9], d_in[10], d_in[11], d_in[12],
                           (const int*)flag, fifo, prog, prog + 128, d_out);
    } else {
        hipLaunchKernelGGL(lstm2_mono, dim3(B_ / BT), dim3(BLK), 0, stream,
                           d_in[0], d_in[1], d_in[2], d_in[3], d_in[4],
                           d_in[5], d_in[6], d_in[7], d_in[8],
                           d_in[9], d_in[10], d_in[11], d_in[12],
                           (const int*)flag, d_out);
    }
}